// Round 1
// baseline (419.008 us; speedup 1.0000x reference)
//
#include <hip/hip_runtime.h>
#include <hip/hip_bf16.h>
#include <cfloat>

#define B_   2
#define NQ_  1024
#define NK_  2048
#define DIM_ 1024
#define H_   16
#define HD_  64

typedef float  floatx4 __attribute__((ext_vector_type(4)));
typedef __bf16 bf16x8  __attribute__((ext_vector_type(8)));

// ---------------------------------------------------------------------------
// Kernel 1: per-batch masked sum of distances  -> msum[b]
// ---------------------------------------------------------------------------
__global__ __launch_bounds__(256) void mean_kernel(
    const float* __restrict__ dist, const int* __restrict__ amask,
    const int* __restrict__ kpmk, float* __restrict__ msum)
{
    const int b = blockIdx.y;
    const float* d  = dist  + (size_t)b * NQ_ * NK_;
    const int*   am = amask + (size_t)b * NQ_ * NK_;
    const int*   km = kpmk  + b * NK_;
    const int total = NQ_ * NK_ / 4;
    float s = 0.f;
    for (int i = blockIdx.x * blockDim.x + threadIdx.x; i < total;
         i += gridDim.x * blockDim.x) {
        const int idx = i * 4;
        const int kk  = idx & (NK_ - 1);
        float4 dv = *(const float4*)(d + idx);
        int4   mv = *(const int4*)(am + idx);
        int4   kv = *(const int4*)(km + kk);
        s += (mv.x && kv.x) ? dv.x : 0.f;
        s += (mv.y && kv.y) ? dv.y : 0.f;
        s += (mv.z && kv.z) ? dv.z : 0.f;
        s += (mv.w && kv.w) ? dv.w : 0.f;
    }
    #pragma unroll
    for (int off = 32; off >= 1; off >>= 1) s += __shfl_down(s, off);
    __shared__ float wsum[4];
    if ((threadIdx.x & 63) == 0) wsum[threadIdx.x >> 6] = s;
    __syncthreads();
    if (threadIdx.x == 0)
        atomicAdd(&msum[b], wsum[0] + wsum[1] + wsum[2] + wsum[3]);
}

// ---------------------------------------------------------------------------
// Kernel 2: fused gate/mask bias  gb = masked ? -alpha*d/mean : -1e30
// ---------------------------------------------------------------------------
__global__ __launch_bounds__(256) void gb_kernel(
    const float* __restrict__ dist, const int* __restrict__ amask,
    const int* __restrict__ kpmk, const float* __restrict__ msum,
    const float* __restrict__ galpha, float* __restrict__ gbout)
{
    const int b = blockIdx.y;
    const float mean  = fmaxf(msum[b] / ((float)(NQ_ * NK_) + 1e-6f), 1e-6f);
    const float alpha = log1pf(__expf(galpha[0]));
    const float c     = -alpha / mean;
    const float* d  = dist  + (size_t)b * NQ_ * NK_;
    const int*   am = amask + (size_t)b * NQ_ * NK_;
    const int*   km = kpmk  + b * NK_;
    float*       g  = gbout + (size_t)b * NQ_ * NK_;
    const int total = NQ_ * NK_ / 4;
    for (int i = blockIdx.x * blockDim.x + threadIdx.x; i < total;
         i += gridDim.x * blockDim.x) {
        const int idx = i * 4;
        const int kk  = idx & (NK_ - 1);
        float4 dv = *(const float4*)(d + idx);
        int4   mv = *(const int4*)(am + idx);
        int4   kv = *(const int4*)(km + kk);
        float4 r;
        r.x = (mv.x && kv.x) ? c * dv.x : -1e30f;
        r.y = (mv.y && kv.y) ? c * dv.y : -1e30f;
        r.z = (mv.z && kv.z) ? c * dv.z : -1e30f;
        r.w = (mv.w && kv.w) ? c * dv.w : -1e30f;
        *(float4*)(g + idx) = r;
    }
}

// ---------------------------------------------------------------------------
// GEMM: Y[m][n] = sum_k A[m][k] * Bw[n][k]    (K = 1024, lda = ldb = 1024)
// 64x64 tile / block, 4 waves, bf16 MFMA 16x16x32.
// MODE 0: -> qp (B,H,NQ,HD) bf16     MODE 1: -> kp (B,H,NK,HD) bf16
// MODE 2: -> vpT (B,H,HD,NK) bf16    MODE 3: -> d_out f32 row-major
// ---------------------------------------------------------------------------
template <bool A_BF16, int MODE>
__global__ __launch_bounds__(256) void gemm_k(
    const void* __restrict__ Aptr, const float* __restrict__ Bw,
    void* __restrict__ Cout)
{
    __shared__ __bf16 As[4][64][8];   // [k-chunk][row][k-within]
    __shared__ __bf16 Bs[4][64][8];
    const int t    = threadIdx.x;
    const int m0   = blockIdx.x * 64, n0 = blockIdx.y * 64;
    const int w    = t >> 6, lane = t & 63;
    const int lrow = lane & 15, quad = lane >> 4;
    const int arow = t >> 2;           // 0..63
    const int sc   = t & 3;            // k-chunk 0..3
    const int s8   = sc * 8;           // k offset within 32

    floatx4 acc[4];
    #pragma unroll
    for (int nb = 0; nb < 4; nb++) acc[nb] = floatx4{0.f, 0.f, 0.f, 0.f};

    for (int k0 = 0; k0 < 1024; k0 += 32) {
        bf16x8 av, bv;
        if (A_BF16) {
            av = *(const bf16x8*)((const __bf16*)Aptr +
                                  (size_t)(m0 + arow) * 1024 + k0 + s8);
        } else {
            const float* ap = (const float*)Aptr +
                              (size_t)(m0 + arow) * 1024 + k0 + s8;
            float4 f0 = *(const float4*)ap;
            float4 f1 = *(const float4*)(ap + 4);
            av[0] = (__bf16)f0.x; av[1] = (__bf16)f0.y;
            av[2] = (__bf16)f0.z; av[3] = (__bf16)f0.w;
            av[4] = (__bf16)f1.x; av[5] = (__bf16)f1.y;
            av[6] = (__bf16)f1.z; av[7] = (__bf16)f1.w;
        }
        {
            const float* bp = Bw + (size_t)(n0 + arow) * 1024 + k0 + s8;
            float4 f0 = *(const float4*)bp;
            float4 f1 = *(const float4*)(bp + 4);
            bv[0] = (__bf16)f0.x; bv[1] = (__bf16)f0.y;
            bv[2] = (__bf16)f0.z; bv[3] = (__bf16)f0.w;
            bv[4] = (__bf16)f1.x; bv[5] = (__bf16)f1.y;
            bv[6] = (__bf16)f1.z; bv[7] = (__bf16)f1.w;
        }
        __syncthreads();   // previous iteration's LDS reads complete
        *(bf16x8*)&As[sc][arow][0] = av;
        *(bf16x8*)&Bs[sc][arow][0] = bv;
        __syncthreads();   // staging visible

        bf16x8 af = *(const bf16x8*)&As[quad][w * 16 + lrow][0];
        #pragma unroll
        for (int nb = 0; nb < 4; nb++) {
            bf16x8 bf = *(const bf16x8*)&Bs[quad][nb * 16 + lrow][0];
            acc[nb] = __builtin_amdgcn_mfma_f32_16x16x32_bf16(af, bf, acc[nb],
                                                              0, 0, 0);
        }
    }

    // epilogue: D row = w*16 + quad*4 + r, col = nb*16 + lrow
    #pragma unroll
    for (int nb = 0; nb < 4; nb++) {
        #pragma unroll
        for (int r = 0; r < 4; r++) {
            const float val = acc[nb][r];
            const int m = m0 + w * 16 + quad * 4 + r;
            const int n = n0 + nb * 16 + lrow;
            if constexpr (MODE == 0) {            // qp: M = B*NQ
                const int b = m >> 10, q = m & 1023;
                const int h = n >> 6,  d = n & 63;
                ((__bf16*)Cout)[(((size_t)(b * 16 + h) * NQ_ + q) << 6) + d] =
                    (__bf16)val;
            } else if constexpr (MODE == 1) {     // kp: M = B*NK
                const int b = m >> 11, key = m & 2047;
                const int h = n >> 6,  d = n & 63;
                ((__bf16*)Cout)[(((size_t)(b * 16 + h) * NK_ + key) << 6) + d] =
                    (__bf16)val;
            } else if constexpr (MODE == 2) {     // vpT: (B,H,HD,NK)
                const int b = m >> 11, key = m & 2047;
                const int h = n >> 6,  d = n & 63;
                ((__bf16*)Cout)[(((size_t)(b * 16 + h) * HD_ + d) << 11) + key] =
                    (__bf16)val;
            } else {                              // final f32 output
                ((float*)Cout)[(size_t)m * 1024 + n] = val;
            }
        }
    }
}

// ---------------------------------------------------------------------------
// Fused flash-style attention with distance gating.
// One wave per 16 q-rows; block = 4 waves share (b,h). 64-key tiles.
// ---------------------------------------------------------------------------
__global__ __launch_bounds__(256) void attn_kernel(
    const __bf16* __restrict__ qp, const __bf16* __restrict__ kp,
    const __bf16* __restrict__ vpT, const float* __restrict__ gb,
    const int* __restrict__ kpmq, __bf16* __restrict__ attnout)
{
    __shared__ __bf16 P2[4][8][16][8];  // [wave][k-chunk][q-row][k-within]
    const int t    = threadIdx.x;
    const int w    = t >> 6, lane = t & 63;
    const int lrow = lane & 15, quad = lane >> 4;
    const int blk  = blockIdx.x;
    const int qt   = blk & 15;          // q-group of 64
    const int bh   = blk >> 4;          // 0..31
    const int b    = bh >> 4, h = bh & 15;
    const int q0   = qt * 64 + w * 16;

    const __bf16* qpb = qp + ((size_t)bh * NQ_ + q0) * HD_;
    const bf16x8 qf0 = *(const bf16x8*)(qpb + lrow * HD_ + quad * 8);
    const bf16x8 qf1 = *(const bf16x8*)(qpb + lrow * HD_ + 32 + quad * 8);

    float mrow[4], Zrow[4], Grow[4];
    floatx4 O[4];
    #pragma unroll
    for (int r = 0; r < 4; r++) { mrow[r] = -FLT_MAX; Zrow[r] = 0.f; Grow[r] = 0.f; }
    #pragma unroll
    for (int nb = 0; nb < 4; nb++) O[nb] = floatx4{0.f, 0.f, 0.f, 0.f};

    const float* gbrow = gb + ((size_t)b * NQ_ + q0 + quad * 4) * NK_;

    for (int kb = 0; kb < NK_; kb += 64) {
        float sv[4][4], gv[4][4];
        #pragma unroll
        for (int c = 0; c < 4; c++) {
            const __bf16* kpb = kp + ((size_t)bh * NK_ + kb + c * 16 + lrow) * HD_;
            bf16x8 kf0 = *(const bf16x8*)(kpb + quad * 8);
            bf16x8 kf1 = *(const bf16x8*)(kpb + 32 + quad * 8);
            floatx4 s4 = floatx4{0.f, 0.f, 0.f, 0.f};
            s4 = __builtin_amdgcn_mfma_f32_16x16x32_bf16(qf0, kf0, s4, 0, 0, 0);
            s4 = __builtin_amdgcn_mfma_f32_16x16x32_bf16(qf1, kf1, s4, 0, 0, 0);
            #pragma unroll
            for (int r = 0; r < 4; r++) {
                const float gbv = gbrow[(size_t)r * NK_ + kb + c * 16 + lrow];
                gv[c][r] = gbv;
                sv[c][r] = (gbv < -1e29f) ? -FLT_MAX : s4[r] * 0.125f;
            }
        }
        #pragma unroll
        for (int r = 0; r < 4; r++) {
            float tm = fmaxf(fmaxf(sv[0][r], sv[1][r]), fmaxf(sv[2][r], sv[3][r]));
            #pragma unroll
            for (int off = 8; off >= 1; off >>= 1)
                tm = fmaxf(tm, __shfl_xor(tm, off));
            const float mnew = fmaxf(mrow[r], tm);
            float sumE = 0.f, sumEG = 0.f;
            #pragma unroll
            for (int c = 0; c < 4; c++) {
                const float e  = __expf(sv[c][r] - mnew);
                const float g  = __expf(gv[c][r]);   // masked -> exp(-1e30)=0
                const float eg = e * g;
                sumE += e; sumEG += eg;
                const int col = c * 16 + lrow;
                P2[w][col >> 3][quad * 4 + r][col & 7] = (__bf16)eg;
            }
            #pragma unroll
            for (int off = 8; off >= 1; off >>= 1) {
                sumE  += __shfl_xor(sumE, off);
                sumEG += __shfl_xor(sumEG, off);
            }
            const float scale = __expf(mrow[r] - mnew);
            Zrow[r] = Zrow[r] * scale + sumE;
            Grow[r] = Grow[r] * scale + sumEG;
            mrow[r] = mnew;
            #pragma unroll
            for (int nb = 0; nb < 4; nb++) O[nb][r] *= scale;
        }
        // PV: P (A-layout via LDS) x V^T fragments (contiguous from vpT)
        #pragma unroll
        for (int tt = 0; tt < 2; tt++) {
            bf16x8 pf = *(const bf16x8*)&P2[w][tt * 4 + quad][lrow][0];
            #pragma unroll
            for (int nb = 0; nb < 4; nb++) {
                const __bf16* vb = vpT + ((size_t)bh * HD_ + nb * 16 + lrow) * NK_ +
                                   kb + tt * 32 + quad * 8;
                bf16x8 vf = *(const bf16x8*)vb;
                O[nb] = __builtin_amdgcn_mfma_f32_16x16x32_bf16(pf, vf, O[nb],
                                                                0, 0, 0);
            }
        }
    }

    // epilogue: out = O/(G + 1e-6*Z) * kpm_q, concat heads, bf16
    #pragma unroll
    for (int r = 0; r < 4; r++) {
        const int q = q0 + quad * 4 + r;
        const float inv = 1.f / (Grow[r] + 1e-6f * Zrow[r]);
        const float km  = kpmq[b * NQ_ + q] ? 1.f : 0.f;
        const float f   = inv * km;
        #pragma unroll
        for (int nb = 0; nb < 4; nb++) {
            attnout[((size_t)b * NQ_ + q) * 1024 + h * HD_ + nb * 16 + lrow] =
                (__bf16)(O[nb][r] * f);
        }
    }
}

// ---------------------------------------------------------------------------
extern "C" void kernel_launch(void* const* d_in, const int* in_sizes, int n_in,
                              void* d_out, int out_size, void* d_ws,
                              size_t ws_size, hipStream_t stream)
{
    const float* q      = (const float*)d_in[0];
    const float* k      = (const float*)d_in[1];
    const float* v      = (const float*)d_in[2];
    const float* dist   = (const float*)d_in[3];
    const int*   amask  = (const int*)d_in[4];
    const int*   kpmq   = (const int*)d_in[5];
    const int*   kpmk   = (const int*)d_in[6];
    const float* Wq     = (const float*)d_in[7];
    const float* Wk     = (const float*)d_in[8];
    const float* Wv     = (const float*)d_in[9];
    const float* Wo     = (const float*)d_in[10];
    const float* galpha = (const float*)d_in[11];

    char* ws = (char*)d_ws;
    float*  msum    = (float*)ws;                          // 256 B
    __bf16* qp      = (__bf16*)(ws + 256);                 // 4 MB
    __bf16* kp      = (__bf16*)(ws + 256 + (4u  << 20));   // 8 MB
    __bf16* vpT     = (__bf16*)(ws + 256 + (12u << 20));   // 8 MB
    float*  gbuf    = (float*)(ws + 256 + (20u << 20));    // 16 MB
    __bf16* attnout = (__bf16*)(ws + 256 + (36u << 20));   // 4 MB

    hipMemsetAsync(msum, 0, 256, stream);
    mean_kernel<<<dim3(128, 2), 256, 0, stream>>>(dist, amask, kpmk, msum);
    gb_kernel<<<dim3(256, 2), 256, 0, stream>>>(dist, amask, kpmk, msum,
                                                galpha, gbuf);
    gemm_k<false, 0><<<dim3(32, 16), 256, 0, stream>>>((const void*)q, Wq, qp);
    gemm_k<false, 1><<<dim3(64, 16), 256, 0, stream>>>((const void*)k, Wk, kp);
    gemm_k<false, 2><<<dim3(64, 16), 256, 0, stream>>>((const void*)v, Wv, vpT);
    attn_kernel<<<512, 256, 0, stream>>>(qp, kp, vpT, gbuf, kpmq, attnout);
    gemm_k<true, 3><<<dim3(32, 16), 256, 0, stream>>>((const void*)attnout, Wo,
                                                      d_out);
}

// Round 2
// 380.587 us; speedup vs baseline: 1.1010x; 1.1010x over previous
//
#include <hip/hip_runtime.h>
#include <hip/hip_bf16.h>
#include <cfloat>

#define B_   2
#define NQ_  1024
#define NK_  2048
#define H_   16
#define HD_  64

typedef float  floatx4 __attribute__((ext_vector_type(4)));
typedef __bf16 bf16x8  __attribute__((ext_vector_type(8)));
typedef __bf16 bf16x4  __attribute__((ext_vector_type(4)));

static __device__ __forceinline__ floatx4 mfma16(bf16x8 a, bf16x8 b, floatx4 c) {
    return __builtin_amdgcn_mfma_f32_16x16x32_bf16(a, b, c, 0, 0, 0);
}

// ---------------------------------------------------------------------------
// Kernel 0: f32 -> bf16 conversion of q,k,v,Wq,Wk,Wv,Wo (one pass)
// ---------------------------------------------------------------------------
struct CvtArgs {
    const float* src[7];
    __bf16*      dst[7];
};

__global__ __launch_bounds__(256) void cvt_kernel(CvtArgs a)
{
    // group = 8 elements. sizes (groups): q 262144, k 524288, v 524288, W 131072x4
    size_t r = (size_t)blockIdx.x * 256 + threadIdx.x;
    int s;
    if (r < 262144)                { s = 0; }
    else if ((r -= 262144) < 524288) { s = 1; }
    else if ((r -= 524288) < 524288) { s = 2; }
    else { r -= 524288; s = 3 + (int)(r >> 17); r &= 131071; }
    const float* sp = a.src[s] + r * 8;
    float4 f0 = *(const float4*)sp;
    float4 f1 = *(const float4*)(sp + 4);
    bf16x8 o;
    o[0] = (__bf16)f0.x; o[1] = (__bf16)f0.y; o[2] = (__bf16)f0.z; o[3] = (__bf16)f0.w;
    o[4] = (__bf16)f1.x; o[5] = (__bf16)f1.y; o[6] = (__bf16)f1.z; o[7] = (__bf16)f1.w;
    *(bf16x8*)(a.dst[s] + r * 8) = o;
}

// ---------------------------------------------------------------------------
// Kernel 1: per-batch masked sum of distances  -> msum[b]
// ---------------------------------------------------------------------------
__global__ __launch_bounds__(256) void mean_kernel(
    const float* __restrict__ dist, const int* __restrict__ amask,
    const int* __restrict__ kpmk, float* __restrict__ msum)
{
    const int b = blockIdx.y;
    const float* d  = dist  + (size_t)b * NQ_ * NK_;
    const int*   am = amask + (size_t)b * NQ_ * NK_;
    const int*   km = kpmk  + b * NK_;
    const int total = NQ_ * NK_ / 4;
    float s = 0.f;
    for (int i = blockIdx.x * blockDim.x + threadIdx.x; i < total;
         i += gridDim.x * blockDim.x) {
        const int idx = i * 4;
        const int kk  = idx & (NK_ - 1);
        float4 dv = *(const float4*)(d + idx);
        int4   mv = *(const int4*)(am + idx);
        int4   kv = *(const int4*)(km + kk);
        s += (mv.x && kv.x) ? dv.x : 0.f;
        s += (mv.y && kv.y) ? dv.y : 0.f;
        s += (mv.z && kv.z) ? dv.z : 0.f;
        s += (mv.w && kv.w) ? dv.w : 0.f;
    }
    #pragma unroll
    for (int off = 32; off >= 1; off >>= 1) s += __shfl_down(s, off);
    __shared__ float wsum[4];
    if ((threadIdx.x & 63) == 0) wsum[threadIdx.x >> 6] = s;
    __syncthreads();
    if (threadIdx.x == 0)
        atomicAdd(&msum[b], wsum[0] + wsum[1] + wsum[2] + wsum[3]);
}

// ---------------------------------------------------------------------------
// Kernel 2: fused gate/mask bias  gb = masked ? -alpha*d/mean : -1e30
// ---------------------------------------------------------------------------
__global__ __launch_bounds__(256) void gb_kernel(
    const float* __restrict__ dist, const int* __restrict__ amask,
    const int* __restrict__ kpmk, const float* __restrict__ msum,
    const float* __restrict__ galpha, float* __restrict__ gbout)
{
    const int b = blockIdx.y;
    const float mean  = fmaxf(msum[b] / ((float)(NQ_ * NK_) + 1e-6f), 1e-6f);
    const float alpha = log1pf(__expf(galpha[0]));
    const float c     = -alpha / mean;
    const float* d  = dist  + (size_t)b * NQ_ * NK_;
    const int*   am = amask + (size_t)b * NQ_ * NK_;
    const int*   km = kpmk  + b * NK_;
    float*       g  = gbout + (size_t)b * NQ_ * NK_;
    const int total = NQ_ * NK_ / 4;
    for (int i = blockIdx.x * blockDim.x + threadIdx.x; i < total;
         i += gridDim.x * blockDim.x) {
        const int idx = i * 4;
        const int kk  = idx & (NK_ - 1);
        float4 dv = *(const float4*)(d + idx);
        int4   mv = *(const int4*)(am + idx);
        int4   kv = *(const int4*)(km + kk);
        float4 r;
        r.x = (mv.x && kv.x) ? c * dv.x : -1e30f;
        r.y = (mv.y && kv.y) ? c * dv.y : -1e30f;
        r.z = (mv.z && kv.z) ? c * dv.z : -1e30f;
        r.w = (mv.w && kv.w) ? c * dv.w : -1e30f;
        *(float4*)(g + idx) = r;
    }
}

// ---------------------------------------------------------------------------
// GEMM: Y[m][n] = sum_k A[m][k] * Bw[n][k]   (all bf16 in, K = 1024)
// 64x64 tile / block, 4 waves, MFMA 16x16x32.
// MODE 0: -> qp (B,H,NQ,HD) bf16     MODE 1: -> kp (B,H,NK,HD) bf16
// MODE 2: -> vpT (B,H,HD,NK) bf16    MODE 3: -> d_out f32 row-major
// ---------------------------------------------------------------------------
template <int MODE>
__global__ __launch_bounds__(256) void gemm_k(
    const __bf16* __restrict__ A, const __bf16* __restrict__ Bw,
    void* __restrict__ Cout)
{
    __shared__ __bf16 As[4][64][8];   // [k-chunk][row][k-within]
    __shared__ __bf16 Bs[4][64][8];
    const int t    = threadIdx.x;
    const int m0   = blockIdx.x * 64, n0 = blockIdx.y * 64;
    const int w    = t >> 6, lane = t & 63;
    const int lrow = lane & 15, quad = lane >> 4;
    const int arow = t >> 2;           // 0..63
    const int sc   = t & 3;            // k-chunk 0..3
    const int s8   = sc * 8;

    floatx4 acc[4];
    #pragma unroll
    for (int nb = 0; nb < 4; nb++) acc[nb] = floatx4{0.f, 0.f, 0.f, 0.f};

    for (int k0 = 0; k0 < 1024; k0 += 32) {
        bf16x8 av = *(const bf16x8*)(A  + (size_t)(m0 + arow) * 1024 + k0 + s8);
        bf16x8 bv = *(const bf16x8*)(Bw + (size_t)(n0 + arow) * 1024 + k0 + s8);
        __syncthreads();
        *(bf16x8*)&As[sc][arow][0] = av;
        *(bf16x8*)&Bs[sc][arow][0] = bv;
        __syncthreads();

        bf16x8 af = *(const bf16x8*)&As[quad][w * 16 + lrow][0];
        #pragma unroll
        for (int nb = 0; nb < 4; nb++) {
            bf16x8 bf = *(const bf16x8*)&Bs[quad][nb * 16 + lrow][0];
            acc[nb] = mfma16(af, bf, acc[nb]);
        }
    }

    #pragma unroll
    for (int nb = 0; nb < 4; nb++) {
        #pragma unroll
        for (int r = 0; r < 4; r++) {
            const float val = acc[nb][r];
            const int m = m0 + w * 16 + quad * 4 + r;
            const int n = n0 + nb * 16 + lrow;
            if constexpr (MODE == 0) {            // qp: M = B*NQ
                const int b = m >> 10, q = m & 1023;
                const int h = n >> 6,  d = n & 63;
                ((__bf16*)Cout)[(((size_t)(b * 16 + h) * NQ_ + q) << 6) + d] =
                    (__bf16)val;
            } else if constexpr (MODE == 1) {     // kp: M = B*NK
                const int b = m >> 11, key = m & 2047;
                const int h = n >> 6,  d = n & 63;
                ((__bf16*)Cout)[(((size_t)(b * 16 + h) * NK_ + key) << 6) + d] =
                    (__bf16)val;
            } else if constexpr (MODE == 2) {     // vpT: (B,H,HD,NK)
                const int b = m >> 11, key = m & 2047;
                const int h = n >> 6,  d = n & 63;
                ((__bf16*)Cout)[(((size_t)(b * 16 + h) * HD_ + d) << 11) + key] =
                    (__bf16)val;
            } else {                              // final f32 output
                ((float*)Cout)[(size_t)m * 1024 + n] = val;
            }
        }
    }
}

// ---------------------------------------------------------------------------
// Fused attention, no max-tracking (scores bounded), gate folded into score.
// Split-K: blockIdx.z selects half of the key range. One wave per 16 q-rows.
// QK computed as mfma(K,Q) so each lane holds 4 consecutive k -> packed b64
// LDS transpose. Emits f32 partials (O, G) summed by combine_kernel.
// ---------------------------------------------------------------------------
__global__ __launch_bounds__(256, 4) void attn_kernel(
    const __bf16* __restrict__ qp, const __bf16* __restrict__ kp,
    const __bf16* __restrict__ vpT, const float* __restrict__ gb,
    float* __restrict__ Opart, float* __restrict__ Gpart)
{
    __shared__ __bf16 Ps[4][16][72];    // per-wave P tile [q][k], stride 144B
    const int t    = threadIdx.x;
    const int w    = t >> 6, lane = t & 63;
    const int lrow = lane & 15, quad = lane >> 4;
    const int qt   = blockIdx.x;        // 0..15
    const int bh   = blockIdx.y;        // 0..31
    const int sp   = blockIdx.z;        // 0..1
    const int b    = bh >> 4;
    const int q0   = qt * 64 + w * 16;
    const int k0   = sp * (NK_ / 2);

    const __bf16* qpb = qp + ((size_t)bh * NQ_ + q0 + lrow) * HD_;
    const bf16x8 qf0 = *(const bf16x8*)(qpb + quad * 8);
    const bf16x8 qf1 = *(const bf16x8*)(qpb + 32 + quad * 8);

    float G = 0.f;
    floatx4 O[4];
    #pragma unroll
    for (int nb = 0; nb < 4; nb++) O[nb] = floatx4{0.f, 0.f, 0.f, 0.f};

    const float*  gbrow = gb + (size_t)(b * NQ_ + q0 + lrow) * NK_;
    const __bf16* kpbb  = kp  + (size_t)bh * NK_ * HD_;
    const __bf16* vpbb  = vpT + (size_t)bh * HD_ * NK_;

    for (int kb = k0; kb < k0 + NK_ / 2; kb += 64) {
        floatx4 s4[4];
        float4  g4[4];
        #pragma unroll
        for (int c = 0; c < 4; c++) {
            const __bf16* kpb = kpbb + (size_t)(kb + c * 16 + lrow) * HD_ + quad * 8;
            bf16x8 kf0 = *(const bf16x8*)kpb;
            bf16x8 kf1 = *(const bf16x8*)(kpb + 32);
            g4[c] = *(const float4*)(gbrow + kb + c * 16 + quad * 4);
            floatx4 acc = floatx4{0.f, 0.f, 0.f, 0.f};
            acc = mfma16(kf0, qf0, acc);
            acc = mfma16(kf1, qf1, acc);
            s4[c] = acc;
        }
        // eg = exp(s/8 + gb); masked gb=-1e30 -> exp -> 0.  Pack 4 k's -> b64.
        #pragma unroll
        for (int c = 0; c < 4; c++) {
            const float e0 = __expf(fmaf(s4[c][0], 0.125f, g4[c].x));
            const float e1 = __expf(fmaf(s4[c][1], 0.125f, g4[c].y));
            const float e2 = __expf(fmaf(s4[c][2], 0.125f, g4[c].z));
            const float e3 = __expf(fmaf(s4[c][3], 0.125f, g4[c].w));
            G += (e0 + e1) + (e2 + e3);
            bf16x4 pk;
            pk[0] = (__bf16)e0; pk[1] = (__bf16)e1;
            pk[2] = (__bf16)e2; pk[3] = (__bf16)e3;
            *(bf16x4*)&Ps[w][lrow][c * 16 + quad * 4] = pk;
        }
        // PV: A = P[q][k] (LDS), B = vpT fragments (contiguous bf16x8)
        #pragma unroll
        for (int tt = 0; tt < 2; tt++) {
            bf16x8 pf = *(const bf16x8*)&Ps[w][lrow][tt * 32 + quad * 8];
            #pragma unroll
            for (int nb = 0; nb < 4; nb++) {
                const __bf16* vb = vpbb + (size_t)(nb * 16 + lrow) * NK_ +
                                   kb + tt * 32 + quad * 8;
                bf16x8 vf = *(const bf16x8*)vb;
                O[nb] = mfma16(pf, vf, O[nb]);
            }
        }
    }

    // G held per-lane for q = lrow; sum across quads
    G += __shfl_xor(G, 16);
    G += __shfl_xor(G, 32);

    float* Ob = Opart + ((size_t)(sp * 32 + bh) * NQ_ + q0) * HD_;
    #pragma unroll
    for (int nb = 0; nb < 4; nb++) {
        #pragma unroll
        for (int r = 0; r < 4; r++) {
            Ob[(size_t)(quad * 4 + r) * HD_ + nb * 16 + lrow] = O[nb][r];
        }
    }
    if (quad == 0)
        Gpart[(size_t)(sp * 32 + bh) * NQ_ + q0 + lrow] = G;
}

// ---------------------------------------------------------------------------
// Combine split-K partials -> attnout bf16 (B, NQ, H*HD), apply kpm_q
// ---------------------------------------------------------------------------
__global__ __launch_bounds__(256) void combine_kernel(
    const float* __restrict__ Opart, const float* __restrict__ Gpart,
    const int* __restrict__ kpmq, __bf16* __restrict__ attnout)
{
    const int t  = blockIdx.x * 256 + threadIdx.x;   // 0 .. 32*1024*16
    const int d4 = (t & 15) * 4;
    const int q  = (t >> 4) & 1023;
    const int bh = t >> 14;
    const int b  = bh >> 4, h = bh & 15;
    const size_t i0 = ((size_t)bh * NQ_ + q) * HD_ + d4;
    const size_t i1 = ((size_t)(32 + bh) * NQ_ + q) * HD_ + d4;
    float4 o0 = *(const float4*)(Opart + i0);
    float4 o1 = *(const float4*)(Opart + i1);
    const float g = Gpart[bh * NQ_ + q] + Gpart[(32 + bh) * NQ_ + q];
    const float f = kpmq[b * NQ_ + q] ? 1.f / (g + 1e-30f) : 0.f;
    bf16x4 r;
    r[0] = (__bf16)((o0.x + o1.x) * f);
    r[1] = (__bf16)((o0.y + o1.y) * f);
    r[2] = (__bf16)((o0.z + o1.z) * f);
    r[3] = (__bf16)((o0.w + o1.w) * f);
    *(bf16x4*)&attnout[((size_t)b * NQ_ + q) * 1024 + h * HD_ + d4] = r;
}

// ---------------------------------------------------------------------------
extern "C" void kernel_launch(void* const* d_in, const int* in_sizes, int n_in,
                              void* d_out, int out_size, void* d_ws,
                              size_t ws_size, hipStream_t stream)
{
    const float* q      = (const float*)d_in[0];
    const float* k      = (const float*)d_in[1];
    const float* v      = (const float*)d_in[2];
    const float* dist   = (const float*)d_in[3];
    const int*   amask  = (const int*)d_in[4];
    const int*   kpmq   = (const int*)d_in[5];
    const int*   kpmk   = (const int*)d_in[6];
    const float* Wq     = (const float*)d_in[7];
    const float* Wk     = (const float*)d_in[8];
    const float* Wv     = (const float*)d_in[9];
    const float* Wo     = (const float*)d_in[10];
    const float* galpha = (const float*)d_in[11];

    char* p = (char*)d_ws;
    float*  msum = (float*)p;                 p += 256;
    __bf16* qb   = (__bf16*)p;                p += (size_t)2097152 * 2;
    __bf16* kb   = (__bf16*)p;                p += (size_t)4194304 * 2;
    __bf16* vb   = (__bf16*)p;                p += (size_t)4194304 * 2;
    __bf16* wqb  = (__bf16*)p;                p += (size_t)1048576 * 2;
    __bf16* wkb  = (__bf16*)p;                p += (size_t)1048576 * 2;
    __bf16* wvb  = (__bf16*)p;                p += (size_t)1048576 * 2;
    __bf16* wob  = (__bf16*)p;                p += (size_t)1048576 * 2;
    __bf16* qp   = (__bf16*)p;                p += (size_t)2097152 * 2;
    __bf16* kpb  = (__bf16*)p;                p += (size_t)4194304 * 2;
    __bf16* vpT  = (__bf16*)p;                p += (size_t)4194304 * 2;
    float*  gbuf = (float*)p;                 p += (size_t)4194304 * 4;
    __bf16* attnout = (__bf16*)p;             p += (size_t)2097152 * 2;
    float*  Opart   = (float*)p;              p += (size_t)2 * 2097152 * 4;
    float*  Gpart   = (float*)p;              p += (size_t)65536 * 4;

    CvtArgs ca;
    ca.src[0] = q;  ca.src[1] = k;  ca.src[2] = v;
    ca.src[3] = Wq; ca.src[4] = Wk; ca.src[5] = Wv; ca.src[6] = Wo;
    ca.dst[0] = qb;  ca.dst[1] = kb;  ca.dst[2] = vb;
    ca.dst[3] = wqb; ca.dst[4] = wkb; ca.dst[5] = wvb; ca.dst[6] = wob;

    hipMemsetAsync(msum, 0, 256, stream);
    cvt_kernel<<<7168, 256, 0, stream>>>(ca);
    mean_kernel<<<dim3(128, 2), 256, 0, stream>>>(dist, amask, kpmk, msum);
    gb_kernel<<<dim3(256, 2), 256, 0, stream>>>(dist, amask, kpmk, msum,
                                                galpha, gbuf);
    gemm_k<0><<<dim3(32, 16), 256, 0, stream>>>(qb, wqb, qp);
    gemm_k<1><<<dim3(64, 16), 256, 0, stream>>>(kb, wkb, kpb);
    gemm_k<2><<<dim3(64, 16), 256, 0, stream>>>(vb, wvb, vpT);
    attn_kernel<<<dim3(16, 32, 2), 256, 0, stream>>>(qp, kpb, vpT, gbuf,
                                                     Opart, Gpart);
    combine_kernel<<<2048, 256, 0, stream>>>(Opart, Gpart, kpmq, attnout);
    gemm_k<3><<<dim3(32, 16), 256, 0, stream>>>(attnout, wob, (float*)d_out);
}

// Round 3
// 275.603 us; speedup vs baseline: 1.5203x; 1.3809x over previous
//
#include <hip/hip_runtime.h>
#include <hip/hip_bf16.h>
#include <cfloat>

#define B_   2
#define NQ_  1024
#define NK_  2048
#define H_   16
#define HD_  64
#define VPAD 2176      // vpT row stride in bf16 elements (17*128)
#define GPAD 2112      // gate row stride in bf16 elements

typedef float  floatx4 __attribute__((ext_vector_type(4)));
typedef __bf16 bf16x8  __attribute__((ext_vector_type(8)));
typedef __bf16 bf16x4  __attribute__((ext_vector_type(4)));

static __device__ __forceinline__ floatx4 mfma16(bf16x8 a, bf16x8 b, floatx4 c) {
    return __builtin_amdgcn_mfma_f32_16x16x32_bf16(a, b, c, 0, 0, 0);
}

// ---------------------------------------------------------------------------
// Kernel 0: f32 -> bf16 conversion of q,k,v,Wq,Wk,Wv,Wo (one pass)
// ---------------------------------------------------------------------------
struct CvtArgs {
    const float* src[7];
    __bf16*      dst[7];
};

__global__ __launch_bounds__(256) void cvt_kernel(CvtArgs a)
{
    size_t r = (size_t)blockIdx.x * 256 + threadIdx.x;
    int s;
    if (r < 262144)                  { s = 0; }
    else if ((r -= 262144) < 524288) { s = 1; }
    else if ((r -= 524288) < 524288) { s = 2; }
    else { r -= 524288; s = 3 + (int)(r >> 17); r &= 131071; }
    const float* sp = a.src[s] + r * 8;
    float4 f0 = *(const float4*)sp;
    float4 f1 = *(const float4*)(sp + 4);
    bf16x8 o;
    o[0] = (__bf16)f0.x; o[1] = (__bf16)f0.y; o[2] = (__bf16)f0.z; o[3] = (__bf16)f0.w;
    o[4] = (__bf16)f1.x; o[5] = (__bf16)f1.y; o[6] = (__bf16)f1.z; o[7] = (__bf16)f1.w;
    *(bf16x8*)(a.dst[s] + r * 8) = o;
}

// ---------------------------------------------------------------------------
// Kernel 1: per-batch masked sum of distances  -> msum[b]
// ---------------------------------------------------------------------------
__global__ __launch_bounds__(256) void mean_kernel(
    const float* __restrict__ dist, const int* __restrict__ amask,
    const int* __restrict__ kpmk, float* __restrict__ msum)
{
    const int b = blockIdx.y;
    const float* d  = dist  + (size_t)b * NQ_ * NK_;
    const int*   am = amask + (size_t)b * NQ_ * NK_;
    const int*   km = kpmk  + b * NK_;
    const int total = NQ_ * NK_ / 4;
    float s = 0.f;
    for (int i = blockIdx.x * blockDim.x + threadIdx.x; i < total;
         i += gridDim.x * blockDim.x) {
        const int idx = i * 4;
        const int kk  = idx & (NK_ - 1);
        float4 dv = *(const float4*)(d + idx);
        int4   mv = *(const int4*)(am + idx);
        int4   kv = *(const int4*)(km + kk);
        s += (mv.x && kv.x) ? dv.x : 0.f;
        s += (mv.y && kv.y) ? dv.y : 0.f;
        s += (mv.z && kv.z) ? dv.z : 0.f;
        s += (mv.w && kv.w) ? dv.w : 0.f;
    }
    #pragma unroll
    for (int off = 32; off >= 1; off >>= 1) s += __shfl_down(s, off);
    __shared__ float wsum[4];
    if ((threadIdx.x & 63) == 0) wsum[threadIdx.x >> 6] = s;
    __syncthreads();
    if (threadIdx.x == 0)
        atomicAdd(&msum[b], wsum[0] + wsum[1] + wsum[2] + wsum[3]);
}

// ---------------------------------------------------------------------------
// Kernel 2: multiplicative gate, bf16, padded rows:
//   gate[b][q][k] = masked ? exp(-alpha*d/mean) : 0
// ---------------------------------------------------------------------------
__global__ __launch_bounds__(256) void gate_kernel(
    const float* __restrict__ dist, const int* __restrict__ amask,
    const int* __restrict__ kpmk, const float* __restrict__ msum,
    const float* __restrict__ galpha, __bf16* __restrict__ gate)
{
    const int b = blockIdx.y;
    const float mean  = fmaxf(msum[b] / ((float)(NQ_ * NK_) + 1e-6f), 1e-6f);
    const float alpha = log1pf(__expf(galpha[0]));
    const float c     = -alpha / mean;
    const int i  = blockIdx.x * 256 + threadIdx.x;   // per-b tile of NQ*NK/4
    const int q  = i >> 9;                            // NK/4 = 512 groups/row
    const int k4 = (i & 511) * 4;
    const size_t src = ((size_t)b * NQ_ + q) * NK_ + k4;
    float4 dv = *(const float4*)(dist + src);
    int4   mv = *(const int4*)(amask + src);
    int4   kv = *(const int4*)(kpmk + b * NK_ + k4);
    bf16x4 r;
    r[0] = (mv.x && kv.x) ? (__bf16)__expf(c * dv.x) : (__bf16)0.f;
    r[1] = (mv.y && kv.y) ? (__bf16)__expf(c * dv.y) : (__bf16)0.f;
    r[2] = (mv.z && kv.z) ? (__bf16)__expf(c * dv.z) : (__bf16)0.f;
    r[3] = (mv.w && kv.w) ? (__bf16)__expf(c * dv.w) : (__bf16)0.f;
    *(bf16x4*)&gate[((size_t)b * NQ_ + q) * GPAD + k4] = r;
}

// ---------------------------------------------------------------------------
// GEMM: Y[m][n] = sum_k A[m][k]*Bw[n][k], K=1024, bf16 in.
// 64x128 tile, 256 threads (4 waves; wave w covers cols w*32..+31), BK=32,
// chunk-major LDS, reg-staged with cross-barrier prefetch.
// MODE 0: -> qp (B,H,NQ,HD)  1: -> kp (B,H,NK,HD)  2: -> vpT (B,H,HD,VPAD)
// MODE 3: -> f32 row-major d_out
// ---------------------------------------------------------------------------
template <int MODE>
__global__ __launch_bounds__(256) void gemm64(
    const __bf16* __restrict__ A, const __bf16* __restrict__ Bw,
    void* __restrict__ Cout)
{
    __shared__ __bf16 As[4 * 64 * 8];     // [chunk][row][8]
    __shared__ __bf16 Bs[4 * 128 * 8];
    const int t    = threadIdx.x;
    const int m0   = blockIdx.x * 64, n0 = blockIdx.y * 128;
    const int w    = t >> 6, lane = t & 63;
    const int lrow = lane & 15, quad = lane >> 4;

    const int rowA = t >> 2, cA = t & 3;
    const int rowB1 = 64 + (t >> 2);
    const __bf16* Ag  = A  + (size_t)(m0 + rowA) * 1024 + cA * 8;
    const __bf16* Bg0 = Bw + (size_t)(n0 + rowA) * 1024 + cA * 8;
    const __bf16* Bg1 = Bw + (size_t)(n0 + rowB1) * 1024 + cA * 8;
    __bf16* AsW  = &As[cA * 512  + rowA * 8];
    __bf16* BsW0 = &Bs[cA * 1024 + rowA * 8];
    __bf16* BsW1 = &Bs[cA * 1024 + rowB1 * 8];

    floatx4 acc[4][2];
    #pragma unroll
    for (int mi = 0; mi < 4; mi++)
        #pragma unroll
        for (int ni = 0; ni < 2; ni++) acc[mi][ni] = floatx4{0.f, 0.f, 0.f, 0.f};

    bf16x8 ar  = *(const bf16x8*)Ag;
    bf16x8 br0 = *(const bf16x8*)Bg0;
    bf16x8 br1 = *(const bf16x8*)Bg1;

    for (int k0 = 0; k0 < 1024; k0 += 32) {
        __syncthreads();                   // prior LDS reads complete
        *(bf16x8*)AsW  = ar;
        *(bf16x8*)BsW0 = br0;
        *(bf16x8*)BsW1 = br1;
        __syncthreads();                   // staging visible
        if (k0 + 32 < 1024) {              // prefetch next tile (overlaps compute)
            ar  = *(const bf16x8*)(Ag  + k0 + 32);
            br0 = *(const bf16x8*)(Bg0 + k0 + 32);
            br1 = *(const bf16x8*)(Bg1 + k0 + 32);
        }
        bf16x8 af[4], bfr[2];
        #pragma unroll
        for (int mi = 0; mi < 4; mi++)
            af[mi] = *(const bf16x8*)&As[quad * 512 + (mi * 16 + lrow) * 8];
        #pragma unroll
        for (int ni = 0; ni < 2; ni++)
            bfr[ni] = *(const bf16x8*)&Bs[quad * 1024 + (w * 32 + ni * 16 + lrow) * 8];
        #pragma unroll
        for (int mi = 0; mi < 4; mi++)
            #pragma unroll
            for (int ni = 0; ni < 2; ni++)
                acc[mi][ni] = mfma16(af[mi], bfr[ni], acc[mi][ni]);
    }

    #pragma unroll
    for (int mi = 0; mi < 4; mi++) {
        #pragma unroll
        for (int ni = 0; ni < 2; ni++) {
            #pragma unroll
            for (int r = 0; r < 4; r++) {
                const float val = acc[mi][ni][r];
                const int m = m0 + mi * 16 + quad * 4 + r;
                const int n = n0 + w * 32 + ni * 16 + lrow;
                if constexpr (MODE == 0) {
                    const int b = m >> 10, q = m & 1023;
                    const int h = n >> 6,  d = n & 63;
                    ((__bf16*)Cout)[(((size_t)(b * 16 + h) * NQ_ + q) << 6) + d] =
                        (__bf16)val;
                } else if constexpr (MODE == 1) {
                    const int b = m >> 11, key = m & 2047;
                    const int h = n >> 6,  d = n & 63;
                    ((__bf16*)Cout)[(((size_t)(b * 16 + h) * NK_ + key) << 6) + d] =
                        (__bf16)val;
                } else if constexpr (MODE == 2) {
                    const int b = m >> 11, key = m & 2047;
                    const int h = n >> 6,  d = n & 63;
                    ((__bf16*)Cout)[((size_t)(b * 16 + h) * HD_ + d) * VPAD + key] =
                        (__bf16)val;
                } else {
                    ((float*)Cout)[(size_t)m * 1024 + n] = val;
                }
            }
        }
    }
}

// ---------------------------------------------------------------------------
// Fused attention. Block = 4 waves, 128 q-rows (wave: 32 q = 2 groups of 16),
// one (bh, split-half). K/V tiles staged block-cooperatively in LDS (loaded
// once per block, conflict-free padded rows), gate bf16 direct loads, P
// transposed per-wave through LDS. No max-tracking (scores bounded).
// ---------------------------------------------------------------------------
__global__ __launch_bounds__(256, 2) void attn_kernel(
    const __bf16* __restrict__ qp, const __bf16* __restrict__ kp,
    const __bf16* __restrict__ vpT, const __bf16* __restrict__ gate,
    float* __restrict__ Opart, float* __restrict__ Gpart)
{
    __shared__ __bf16 Ks[64 * 72];        // [key][hd], stride 72
    __shared__ __bf16 Vt[64 * 72];        // [hd][key], stride 72
    __shared__ __bf16 Ps[4][32 * 72];     // per-wave P [q][k], stride 72
    const int t    = threadIdx.x;
    const int w    = t >> 6, lane = t & 63;
    const int lrow = lane & 15, quad = lane >> 4;
    const int qt   = blockIdx.x;          // 0..7
    const int bh   = blockIdx.y;          // 0..31
    const int sp   = blockIdx.z;          // 0..1
    const int b    = bh >> 4;
    const int q0   = qt * 128 + w * 32;
    const int k0   = sp * (NK_ / 2);

    // Q fragments for both q-groups (held in regs all loop)
    bf16x8 qf[2][2];
    #pragma unroll
    for (int qg = 0; qg < 2; qg++) {
        const __bf16* qb = qp + ((size_t)bh * NQ_ + q0 + qg * 16 + lrow) * HD_ +
                           quad * 8;
        qf[qg][0] = *(const bf16x8*)qb;
        qf[qg][1] = *(const bf16x8*)(qb + 32);
    }

    // cooperative staging coords: 512 lane-slots = 64 rows x 8 col-chunks
    const int srow0 = t >> 3,        sc0 = t & 7;   // part 0: rows 0..31
    const int srow1 = 32 + (t >> 3), sc1 = t & 7;   // part 1: rows 32..63
    const __bf16* Kg = kp  + (size_t)bh * NK_ * HD_;
    const __bf16* Vg = vpT + (size_t)bh * HD_ * VPAD;
    __bf16* KsW0 = &Ks[srow0 * 72 + sc0 * 8];
    __bf16* KsW1 = &Ks[srow1 * 72 + sc1 * 8];
    __bf16* VtW0 = &Vt[srow0 * 72 + sc0 * 8];
    __bf16* VtW1 = &Vt[srow1 * 72 + sc1 * 8];

    const __bf16* grow[2];
    #pragma unroll
    for (int qg = 0; qg < 2; qg++)
        grow[qg] = gate + ((size_t)b * NQ_ + q0 + qg * 16 + lrow) * GPAD;

    float G[2] = {0.f, 0.f};
    floatx4 O[2][4];
    #pragma unroll
    for (int qg = 0; qg < 2; qg++)
        #pragma unroll
        for (int nb = 0; nb < 4; nb++) O[qg][nb] = floatx4{0.f, 0.f, 0.f, 0.f};

    bf16x8 kr0, kr1, vr0, vr1;
    bf16x4 gr[2][4];
    auto loadt = [&](int kb) {
        kr0 = *(const bf16x8*)(Kg + (size_t)(kb + srow0) * HD_ + sc0 * 8);
        kr1 = *(const bf16x8*)(Kg + (size_t)(kb + srow1) * HD_ + sc1 * 8);
        vr0 = *(const bf16x8*)(Vg + (size_t)srow0 * VPAD + kb + sc0 * 8);
        vr1 = *(const bf16x8*)(Vg + (size_t)srow1 * VPAD + kb + sc1 * 8);
        #pragma unroll
        for (int qg = 0; qg < 2; qg++)
            #pragma unroll
            for (int c = 0; c < 4; c++)
                gr[qg][c] = *(const bf16x4*)(grow[qg] + kb + c * 16 + quad * 4);
    };
    loadt(k0);

    for (int kb = k0; kb < k0 + NK_ / 2; kb += 64) {
        __syncthreads();                   // prior tile's LDS reads done
        *(bf16x8*)KsW0 = kr0;
        *(bf16x8*)KsW1 = kr1;
        *(bf16x8*)VtW0 = vr0;
        *(bf16x8*)VtW1 = vr1;
        __syncthreads();                   // staging visible

        bf16x4 gcur[2][4];
        #pragma unroll
        for (int qg = 0; qg < 2; qg++)
            #pragma unroll
            for (int c = 0; c < 4; c++) gcur[qg][c] = gr[qg][c];
        if (kb + 64 < k0 + NK_ / 2) loadt(kb + 64);   // prefetch next tile

        // QK^T: A = K rows (shared frags), B = Q regs -> S[key][q]
        bf16x8 kf0[4], kf1[4];
        #pragma unroll
        for (int c = 0; c < 4; c++) {
            kf0[c] = *(const bf16x8*)&Ks[(c * 16 + lrow) * 72 + quad * 8];
            kf1[c] = *(const bf16x8*)&Ks[(c * 16 + lrow) * 72 + 32 + quad * 8];
        }
        floatx4 s4[2][4];
        #pragma unroll
        for (int qg = 0; qg < 2; qg++)
            #pragma unroll
            for (int c = 0; c < 4; c++) {
                floatx4 a = floatx4{0.f, 0.f, 0.f, 0.f};
                a = mfma16(kf0[c], qf[qg][0], a);
                a = mfma16(kf1[c], qf[qg][1], a);
                s4[qg][c] = a;
            }

        // eg = exp(s/8)*gate  (masked gate = 0); transpose via per-wave LDS
        #pragma unroll
        for (int qg = 0; qg < 2; qg++) {
            #pragma unroll
            for (int c = 0; c < 4; c++) {
                const float e0 = __expf(s4[qg][c][0] * 0.125f) * (float)gcur[qg][c][0];
                const float e1 = __expf(s4[qg][c][1] * 0.125f) * (float)gcur[qg][c][1];
                const float e2 = __expf(s4[qg][c][2] * 0.125f) * (float)gcur[qg][c][2];
                const float e3 = __expf(s4[qg][c][3] * 0.125f) * (float)gcur[qg][c][3];
                G[qg] += (e0 + e1) + (e2 + e3);
                bf16x4 pk;
                pk[0] = (__bf16)e0; pk[1] = (__bf16)e1;
                pk[2] = (__bf16)e2; pk[3] = (__bf16)e3;
                *(bf16x4*)&Ps[w][(qg * 16 + lrow) * 72 + c * 16 + quad * 4] = pk;
            }
        }

        // PV: A = P (LDS), B = V^T frags (shared, from LDS)
        bf16x8 pf[2][2];
        #pragma unroll
        for (int qg = 0; qg < 2; qg++)
            #pragma unroll
            for (int tt = 0; tt < 2; tt++)
                pf[qg][tt] = *(const bf16x8*)
                    &Ps[w][(qg * 16 + lrow) * 72 + tt * 32 + quad * 8];
        #pragma unroll
        for (int tt = 0; tt < 2; tt++)
            #pragma unroll
            for (int nb = 0; nb < 4; nb++) {
                bf16x8 vf = *(const bf16x8*)
                    &Vt[(nb * 16 + lrow) * 72 + tt * 32 + quad * 8];
                #pragma unroll
                for (int qg = 0; qg < 2; qg++)
                    O[qg][nb] = mfma16(pf[qg][tt], vf, O[qg][nb]);
            }
    }

    #pragma unroll
    for (int qg = 0; qg < 2; qg++) {
        G[qg] += __shfl_xor(G[qg], 16);
        G[qg] += __shfl_xor(G[qg], 32);
    }
    float* Ob = Opart + ((size_t)(sp * 32 + bh) * NQ_ + q0) * HD_;
    #pragma unroll
    for (int qg = 0; qg < 2; qg++)
        #pragma unroll
        for (int nb = 0; nb < 4; nb++)
            #pragma unroll
            for (int r = 0; r < 4; r++)
                Ob[(size_t)(qg * 16 + quad * 4 + r) * HD_ + nb * 16 + lrow] =
                    O[qg][nb][r];
    if (quad == 0) {
        #pragma unroll
        for (int qg = 0; qg < 2; qg++)
            Gpart[(size_t)(sp * 32 + bh) * NQ_ + q0 + qg * 16 + lrow] = G[qg];
    }
}

// ---------------------------------------------------------------------------
// Combine split-K partials -> attnout bf16 (B, NQ, H*HD), apply kpm_q
// ---------------------------------------------------------------------------
__global__ __launch_bounds__(256) void combine_kernel(
    const float* __restrict__ Opart, const float* __restrict__ Gpart,
    const int* __restrict__ kpmq, __bf16* __restrict__ attnout)
{
    const int t  = blockIdx.x * 256 + threadIdx.x;
    const int d4 = (t & 15) * 4;
    const int q  = (t >> 4) & 1023;
    const int bh = t >> 14;
    const int b  = bh >> 4, h = bh & 15;
    const size_t i0 = ((size_t)bh * NQ_ + q) * HD_ + d4;
    const size_t i1 = ((size_t)(32 + bh) * NQ_ + q) * HD_ + d4;
    float4 o0 = *(const float4*)(Opart + i0);
    float4 o1 = *(const float4*)(Opart + i1);
    const float g = Gpart[bh * NQ_ + q] + Gpart[(32 + bh) * NQ_ + q];
    const float f = kpmq[b * NQ_ + q] ? 1.f / (g + 1e-30f) : 0.f;
    bf16x4 r;
    r[0] = (__bf16)((o0.x + o1.x) * f);
    r[1] = (__bf16)((o0.y + o1.y) * f);
    r[2] = (__bf16)((o0.z + o1.z) * f);
    r[3] = (__bf16)((o0.w + o1.w) * f);
    *(bf16x4*)&attnout[((size_t)b * NQ_ + q) * 1024 + h * HD_ + d4] = r;
}

// ---------------------------------------------------------------------------
extern "C" void kernel_launch(void* const* d_in, const int* in_sizes, int n_in,
                              void* d_out, int out_size, void* d_ws,
                              size_t ws_size, hipStream_t stream)
{
    const float* q      = (const float*)d_in[0];
    const float* k      = (const float*)d_in[1];
    const float* v      = (const float*)d_in[2];
    const float* dist   = (const float*)d_in[3];
    const int*   amask  = (const int*)d_in[4];
    const int*   kpmq   = (const int*)d_in[5];
    const int*   kpmk   = (const int*)d_in[6];
    const float* Wq     = (const float*)d_in[7];
    const float* Wk     = (const float*)d_in[8];
    const float* Wv     = (const float*)d_in[9];
    const float* Wo     = (const float*)d_in[10];
    const float* galpha = (const float*)d_in[11];

    char* p = (char*)d_ws;
    float*  msum = (float*)p;                 p += 256;
    __bf16* qb   = (__bf16*)p;                p += (size_t)2097152 * 2;
    __bf16* kb   = (__bf16*)p;                p += (size_t)4194304 * 2;
    __bf16* vb   = (__bf16*)p;                p += (size_t)4194304 * 2;
    __bf16* wqb  = (__bf16*)p;                p += (size_t)1048576 * 2;
    __bf16* wkb  = (__bf16*)p;                p += (size_t)1048576 * 2;
    __bf16* wvb  = (__bf16*)p;                p += (size_t)1048576 * 2;
    __bf16* wob  = (__bf16*)p;                p += (size_t)1048576 * 2;
    __bf16* qp   = (__bf16*)p;                p += (size_t)2097152 * 2;
    __bf16* kpb  = (__bf16*)p;                p += (size_t)4194304 * 2;
    __bf16* vpT  = (__bf16*)p;                p += (size_t)32 * 64 * VPAD * 2;
    __bf16* gate = (__bf16*)p;                p += (size_t)2048 * GPAD * 2;
    __bf16* attnout = (__bf16*)p;             p += (size_t)2097152 * 2;
    float*  Opart   = (float*)p;              p += (size_t)2 * 2097152 * 4;
    float*  Gpart   = (float*)p;              p += (size_t)65536 * 4;

    CvtArgs ca;
    ca.src[0] = q;  ca.src[1] = k;  ca.src[2] = v;
    ca.src[3] = Wq; ca.src[4] = Wk; ca.src[5] = Wv; ca.src[6] = Wo;
    ca.dst[0] = qb;  ca.dst[1] = kb;  ca.dst[2] = vb;
    ca.dst[3] = wqb; ca.dst[4] = wkb; ca.dst[5] = wvb; ca.dst[6] = wob;

    hipMemsetAsync(msum, 0, 256, stream);
    cvt_kernel<<<7168, 256, 0, stream>>>(ca);
    mean_kernel<<<dim3(128, 2), 256, 0, stream>>>(dist, amask, kpmk, msum);
    gate_kernel<<<dim3(2048, 2), 256, 0, stream>>>(dist, amask, kpmk, msum,
                                                   galpha, gate);
    gemm64<0><<<dim3(32, 8), 256, 0, stream>>>(qb, wqb, qp);
    gemm64<1><<<dim3(64, 8), 256, 0, stream>>>(kb, wkb, kpb);
    gemm64<2><<<dim3(64, 8), 256, 0, stream>>>(vb, wvb, vpT);
    attn_kernel<<<dim3(8, 32, 2), 256, 0, stream>>>(qp, kpb, vpT, gate,
                                                    Opart, Gpart);
    combine_kernel<<<2048, 256, 0, stream>>>(Opart, Gpart, kpmq, attnout);
    gemm64<3><<<dim3(32, 8), 256, 0, stream>>>(attnout, wob, (float*)d_out);
}